// Round 5
// baseline (508.638 us; speedup 1.0000x reference)
//
#include <hip/hip_runtime.h>

typedef unsigned short u16;
typedef __attribute__((ext_vector_type(8))) short short8;
typedef __attribute__((ext_vector_type(8))) __bf16 bf16x8;
typedef __attribute__((ext_vector_type(4))) float floatx4;

#define BATCH 128
#define SEQ 197
#define CH 768
#define NH 12
#define HD 64
#define MROWS (BATCH * SEQ)   // 25216 = 197 * 128 exactly
#define MPAD 25344            // 99 * 256, for 256-row M-tiles

#define TM 256
#define TN 256
#define TK 64

__device__ __forceinline__ floatx4 mfma16(short8 a, short8 b, floatx4 c) {
  return __builtin_amdgcn_mfma_f32_16x16x32_bf16(
      __builtin_bit_cast(bf16x8, a), __builtin_bit_cast(bf16x8, b), c, 0, 0, 0);
}

__device__ __forceinline__ u16 f2bf(float f) {
  unsigned u = __builtin_bit_cast(unsigned, f);
  return (u16)((u + 0x7fffu + ((u >> 16) & 1u)) >> 16);
}

// async global->LDS, 16B per lane; LDS dest is wave-uniform base + lane*16
__device__ __forceinline__ void async16(const u16* g, u16* s) {
  __builtin_amdgcn_global_load_lds((const __attribute__((address_space(1))) void*)g,
                                   (__attribute__((address_space(3))) void*)s, 16, 0, 0);
}

// ---------------- fused preprocessing: 3x fp32->bf16 + relb gather + x pad zero ----------------
__global__ __launch_bounds__(256) void preproc(const float4* __restrict__ x, ushort4* __restrict__ xo, int n0,
                                               const float4* __restrict__ w1, ushort4* __restrict__ w1o, int n1,
                                               const float4* __restrict__ w2, ushort4* __restrict__ w2o, int n2,
                                               const int* __restrict__ idx, const float* __restrict__ table,
                                               float* __restrict__ relb) {
  int i = blockIdx.x * 256 + threadIdx.x;
  const float4* in; ushort4* out; int j;
  if (i < n0) { in = x; out = xo; j = i; }
  else if (i < n0 + n1) { in = w1; out = w1o; j = i - n0; }
  else if (i < n0 + n1 + n2) { in = w2; out = w2o; j = i - n0 - n1; }
  else {
    int t = i - (n0 + n1 + n2);
    if (t < SEQ * SEQ) {
      int id = idx[t];
      const float* row = table + id * NH;
#pragma unroll
      for (int h = 0; h < NH; h++) relb[h * (SEQ * SEQ) + t] = row[h];
    } else {
      int p = t - SEQ * SEQ;
      if (p < (MPAD - MROWS) * CH / 4) {
        ushort4 z = {0, 0, 0, 0};
        xo[n0 + p] = z;   // zero the 128 pad rows of x_bf
      }
    }
    return;
  }
  float4 v = in[j];
  ushort4 o;
  o.x = f2bf(v.x); o.y = f2bf(v.y); o.z = f2bf(v.z); o.w = f2bf(v.w);
  out[j] = o;
}

// ---- shared 256x256x64 8-wave phase-split GEMM core (macros) ----
// LDS layout per matrix tile: [256 rows][64 k] u16, 8 granules of 8 u16 per row,
// logical granule g stored at physical p = g ^ (row & 7)  (bank-conflict-free under
// the 8-lane-group model; staging writes are linear so the SOURCE addr is pre-swizzled).

#define STAGE8(Sb_, kk_)                                                       \
  do {                                                                         \
    u16* sa_ = (Sb_) + wave * 8 * TK;                                          \
    u16* sb_ = (Sb_) + TM * TK + wave * 8 * TK;                                \
    const u16* ga_ = Agp + (kk_);                                              \
    const u16* gb_ = Bgp + (kk_);                                              \
    _Pragma("unroll")                                                          \
    for (int r_ = 0; r_ < 4; r_++)                                             \
      async16(ga_ + (size_t)r_ * 64 * CH, sa_ + r_ * 64 * TK);                 \
    _Pragma("unroll")                                                          \
    for (int r_ = 0; r_ < 4; r_++)                                             \
      async16(gb_ + (size_t)r_ * 64 * CH, sb_ + r_ * 64 * TK);                 \
  } while (0)

#define QUAD(Sb_, qr_, qc_)                                                    \
  do {                                                                         \
    const u16* sa_ = (Sb_);                                                    \
    const u16* sb_ = (Sb_) + TM * TK;                                          \
    int pof0_ = ((quad) ^ (c16 & 7)) * 8;                                      \
    int pof1_ = ((4 + quad) ^ (c16 & 7)) * 8;                                  \
    short8 av_[4][2], bv_[2][2];                                               \
    _Pragma("unroll")                                                          \
    for (int i_ = 0; i_ < 4; i_++) {                                           \
      int R_ = wm * 128 + ((qr_) * 4 + i_) * 16 + c16;                         \
      av_[i_][0] = *(const short8*)(sa_ + R_ * TK + pof0_);                    \
      av_[i_][1] = *(const short8*)(sa_ + R_ * TK + pof1_);                    \
    }                                                                          \
    _Pragma("unroll")                                                          \
    for (int j_ = 0; j_ < 2; j_++) {                                           \
      int R_ = wn * 64 + ((qc_) * 2 + j_) * 16 + c16;                          \
      bv_[j_][0] = *(const short8*)(sb_ + R_ * TK + pof0_);                    \
      bv_[j_][1] = *(const short8*)(sb_ + R_ * TK + pof1_);                    \
    }                                                                          \
    __builtin_amdgcn_s_setprio(1);                                             \
    _Pragma("unroll")                                                          \
    for (int i_ = 0; i_ < 4; i_++)                                             \
      _Pragma("unroll")                                                        \
      for (int j_ = 0; j_ < 2; j_++) {                                         \
        acc[(qr_) * 4 + i_][(qc_) * 2 + j_] =                                  \
            mfma16(av_[i_][0], bv_[j_][0], acc[(qr_) * 4 + i_][(qc_) * 2 + j_]); \
        acc[(qr_) * 4 + i_][(qc_) * 2 + j_] =                                  \
            mfma16(av_[i_][1], bv_[j_][1], acc[(qr_) * 4 + i_][(qc_) * 2 + j_]); \
      }                                                                        \
    __builtin_amdgcn_s_setprio(0);                                             \
  } while (0)

#define PBAR()                                                                 \
  do {                                                                         \
    asm volatile("" ::: "memory");                                             \
    __builtin_amdgcn_s_barrier();                                              \
    asm volatile("" ::: "memory");                                             \
  } while (0)

#define GEMM_PRE_AND_LOOP(Amat_, Wmat_, NBLK_)                                 \
  __shared__ u16 S[2][2 * TM * TK]; /* 128 KB */                               \
  int tid = threadIdx.x;                                                       \
  int wave = tid >> 6, lane = tid & 63, quad = lane >> 4, c16 = lane & 15;     \
  int wm = wave >> 2, wn = wave & 3;                                           \
  int nwg = gridDim.x;                                                         \
  int orig = blockIdx.x;                                                       \
  int xcd = orig & 7, pos = orig >> 3;                                         \
  int qq = nwg >> 3, rr = nwg & 7;                                             \
  int lid = (xcd < rr ? xcd * (qq + 1) : rr * (qq + 1) + (xcd - rr) * qq) + pos; \
  int mblk = lid / (NBLK_), nblk = lid - mblk * (NBLK_);                       \
  int m0 = mblk * TM, n0 = nblk * TN;                                          \
  int lr = lane >> 3;                                                          \
  int lg = (lane & 7) ^ lr;                                                    \
  const u16* Agp = (Amat_) + (size_t)(m0 + wave * 8 + lr) * CH + lg * 8;       \
  const u16* Bgp = (Wmat_) + (size_t)(n0 + wave * 8 + lr) * CH + lg * 8;       \
  floatx4 acc[8][4] = {};                                                      \
  STAGE8(&S[0][0], 0);                                                         \
  asm volatile("s_waitcnt vmcnt(0)" ::: "memory");                             \
  __builtin_amdgcn_s_barrier();                                                \
  asm volatile("" ::: "memory");                                               \
  for (int kt = 0; kt < CH / TK; ++kt) {                                       \
    int cb = kt & 1;                                                           \
    if (kt < CH / TK - 1) STAGE8(&S[cb ^ 1][0], (kt + 1) * TK);                \
    QUAD(&S[cb][0], 0, 0); PBAR();                                             \
    QUAD(&S[cb][0], 0, 1); PBAR();                                             \
    QUAD(&S[cb][0], 1, 0); PBAR();                                             \
    QUAD(&S[cb][0], 1, 1);                                                     \
    if (kt < CH / TK - 1) asm volatile("s_waitcnt vmcnt(0)" ::: "memory");     \
    PBAR();                                                                    \
  }

// ---------------- QKV GEMM: 256x256 tile, 8 waves, 4-phase split ----------------
// grid 99*9 = 891 1-D, XCD-chunked swizzle. block 512.
__global__ __launch_bounds__(512, 2) void gemm_qkv(const u16* __restrict__ A,
                                                   const u16* __restrict__ W,
                                                   const float* __restrict__ qb,
                                                   const float* __restrict__ vb,
                                                   u16* __restrict__ q_buf,
                                                   u16* __restrict__ k_buf,
                                                   u16* __restrict__ v_buf) {
  GEMM_PRE_AND_LOOP(A, W, 9)

#pragma unroll
  for (int j = 0; j < 4; j++) {
    int gcol = n0 + wn * 64 + j * 16 + c16;    // 0..2303
    int t = gcol / CH;                          // 0=q 1=k 2=v
    int rem = gcol - t * CH;                    // h*64+d
    int h = rem >> 6, d = rem & 63;
    float badd = (t == 0) ? qb[rem] : (t == 2 ? vb[rem] : 0.0f);
    u16* dst = (t == 0) ? q_buf : (t == 1 ? k_buf : v_buf);
#pragma unroll
    for (int i = 0; i < 8; i++) {
#pragma unroll
      for (int r = 0; r < 4; r++) {
        int grow = m0 + wm * 128 + i * 16 + quad * 4 + r;
        if (grow < MROWS) {
          int bb = grow / SEQ;
          int n = grow - bb * SEQ;
          dst[(((size_t)bb * NH + h) * SEQ + n) * HD + d] = f2bf(acc[i][j][r] + badd);
        }
      }
    }
  }
}

// ---------------- proj GEMM: 256x256 tile, 8 waves, 4-phase split, fp32 out ----------------
// grid 99*3 = 297 1-D, XCD-chunked swizzle.
__global__ __launch_bounds__(512, 2) void gemm_proj(const u16* __restrict__ A,
                                                    const u16* __restrict__ W,
                                                    const float* __restrict__ bias,
                                                    float* __restrict__ out) {
  GEMM_PRE_AND_LOOP(A, W, 3)

#pragma unroll
  for (int j = 0; j < 4; j++) {
    int gcol = n0 + wn * 64 + j * 16 + c16;
    float bj = bias[gcol];
#pragma unroll
    for (int i = 0; i < 8; i++) {
#pragma unroll
      for (int r = 0; r < 4; r++) {
        int grow = m0 + wm * 128 + i * 16 + quad * 4 + r;
        if (grow < MROWS) out[(size_t)grow * CH + gcol] = acc[i][j][r] + bj;
      }
    }
  }
}

// ---------------- attention: one block per (h, b), register softmax, setprio on MFMA ----------------
#define PS 232
#define VS 264

__global__ __launch_bounds__(256, 2) void attn(const u16* __restrict__ q_buf,
                                               const u16* __restrict__ k_buf,
                                               const u16* __restrict__ v_buf,
                                               const float* __restrict__ relb,
                                               u16* __restrict__ attn_out) {
  __shared__ u16 Vt[64 * VS];
  __shared__ u16 P[4 * 16 * PS];

  int h = blockIdx.x, b = blockIdx.y;
  int tid = threadIdx.x, wave = tid >> 6, lane = tid & 63, quad = lane >> 4, c16 = lane & 15;
  size_t bh = (size_t)b * NH + h;
  const u16* Q = q_buf + bh * SEQ * HD;
  const u16* Kp = k_buf + bh * SEQ * HD;
  const u16* Vp = v_buf + bh * SEQ * HD;
  const float* RB = relb + (size_t)h * (SEQ * SEQ);

  {
    int mrow = tid >> 3, dbase = (tid & 7) * 8;
#pragma unroll
    for (int i = 0; i < 7; i++) {
      int m = mrow + 32 * i;
      if (m < SEQ) {
        ushort4 v0 = *(const ushort4*)(Vp + m * HD + dbase);
        ushort4 v1 = *(const ushort4*)(Vp + m * HD + dbase + 4);
        Vt[(dbase + 0) * VS + m] = v0.x;
        Vt[(dbase + 1) * VS + m] = v0.y;
        Vt[(dbase + 2) * VS + m] = v0.z;
        Vt[(dbase + 3) * VS + m] = v0.w;
        Vt[(dbase + 4) * VS + m] = v1.x;
        Vt[(dbase + 5) * VS + m] = v1.y;
        Vt[(dbase + 6) * VS + m] = v1.z;
        Vt[(dbase + 7) * VS + m] = v1.w;
      } else {
#pragma unroll
        for (int dd = 0; dd < 8; dd++) Vt[(dbase + dd) * VS + m] = 0;
      }
    }
  }
  __syncthreads();

  u16* Pw = P + wave * 16 * PS;
  for (int rt = wave; rt < 13; rt += 4) {
    int q0 = rt * 16;
    int qr = min(q0 + c16, SEQ - 1);
    short8 qa0 = *(const short8*)(Q + qr * HD + quad * 8);
    short8 qa1 = *(const short8*)(Q + qr * HD + 32 + quad * 8);

    floatx4 sacc[13];
    __builtin_amdgcn_s_setprio(1);
#pragma unroll
    for (int nt = 0; nt < 13; nt++) {
      int mc = min(nt * 16 + c16, SEQ - 1);
      floatx4 a = {0.f, 0.f, 0.f, 0.f};
      a = mfma16(qa0, *(const short8*)(Kp + mc * HD + quad * 8), a);
      a = mfma16(qa1, *(const short8*)(Kp + mc * HD + 32 + quad * 8), a);
      sacc[nt] = a;
    }
    __builtin_amdgcn_s_setprio(0);

#pragma unroll
    for (int r = 0; r < 4; r++) {
      int rq = min(q0 + quad * 4 + r, SEQ - 1);
      const float* RBr = RB + (size_t)rq * SEQ;
      float mx = -1e30f;
#pragma unroll
      for (int nt = 0; nt < 13; nt++) {
        int m = nt * 16 + c16;
        float s = -1e30f;
        if (m < SEQ) s = sacc[nt][r] * 0.125f + RBr[m];
        sacc[nt][r] = s;
        mx = fmaxf(mx, s);
      }
      mx = fmaxf(mx, __shfl_xor(mx, 1));
      mx = fmaxf(mx, __shfl_xor(mx, 2));
      mx = fmaxf(mx, __shfl_xor(mx, 4));
      mx = fmaxf(mx, __shfl_xor(mx, 8));
      float sum = 0.f;
#pragma unroll
      for (int nt = 0; nt < 13; nt++) {
        float e = __expf(sacc[nt][r] - mx);
        sacc[nt][r] = e;
        sum += e;
      }
      sum += __shfl_xor(sum, 1);
      sum += __shfl_xor(sum, 2);
      sum += __shfl_xor(sum, 4);
      sum += __shfl_xor(sum, 8);
      float inv = 1.f / sum;
      int prow = (quad * 4 + r) * PS;
#pragma unroll
      for (int nt = 0; nt < 13; nt++)
        Pw[prow + nt * 16 + c16] = f2bf(sacc[nt][r] * inv);
      Pw[prow + 208 + c16] = 0;
    }

    floatx4 oacc[4] = {};
    __builtin_amdgcn_s_setprio(1);
#pragma unroll
    for (int ks = 0; ks < 7; ks++) {
      short8 a = *(const short8*)(Pw + c16 * PS + ks * 32 + quad * 8);
#pragma unroll
      for (int dt = 0; dt < 4; dt++) {
        short8 bb = *(const short8*)(Vt + (dt * 16 + c16) * VS + ks * 32 + quad * 8);
        oacc[dt] = mfma16(a, bb, oacc[dt]);
      }
    }
    __builtin_amdgcn_s_setprio(0);
#pragma unroll
    for (int dt = 0; dt < 4; dt++) {
      int d = dt * 16 + c16;
#pragma unroll
      for (int r = 0; r < 4; r++) {
        int grow = q0 + quad * 4 + r;
        if (grow < SEQ)
          attn_out[((size_t)b * SEQ + grow) * CH + h * HD + d] = f2bf(oacc[dt][r]);
      }
    }
  }
}

extern "C" void kernel_launch(void* const* d_in, const int* in_sizes, int n_in,
                              void* d_out, int out_size, void* d_ws, size_t ws_size,
                              hipStream_t stream) {
  const float* x      = (const float*)d_in[0];
  const float* qkv_w  = (const float*)d_in[1];
  const float* q_bias = (const float*)d_in[2];
  const float* v_bias = (const float*)d_in[3];
  const float* table  = (const float*)d_in[4];
  const float* proj_w = (const float*)d_in[5];
  const float* proj_b = (const float*)d_in[6];
  const int*   rel_ix = (const int*)d_in[7];
  float* out = (float*)d_out;

  char* ws = (char*)d_ws;
  size_t off = 0;
  u16* x_bf  = (u16*)(ws + off); off += (size_t)MPAD * CH * 2;   // padded to 25344 rows
  u16* wq_bf = (u16*)(ws + off); off += (size_t)3 * CH * CH * 2;
  u16* wp_bf = (u16*)(ws + off); off += (size_t)CH * CH * 2;
  u16* q_buf = (u16*)(ws + off); off += (size_t)MROWS * CH * 2;
  u16* k_buf = (u16*)(ws + off); off += (size_t)MROWS * CH * 2;
  u16* v_buf = (u16*)(ws + off); off += (size_t)MROWS * CH * 2;
  u16* ao_bf = (u16*)(ws + off); off += (size_t)MPAD * CH * 2;   // padded (pad rows read but masked)
  float* relb = (float*)(ws + off);

  int n0 = MROWS * CH / 4;
  int n1 = 3 * CH * CH / 4;
  int n2 = CH * CH / 4;
  int npad = (MPAD - MROWS) * CH / 4;
  int ntot = n0 + n1 + n2 + SEQ * SEQ + npad;
  preproc<<<(ntot + 255) / 256, 256, 0, stream>>>(
      (const float4*)x, (ushort4*)x_bf, n0,
      (const float4*)qkv_w, (ushort4*)wq_bf, n1,
      (const float4*)proj_w, (ushort4*)wp_bf, n2,
      rel_ix, table, relb);
  gemm_qkv<<<dim3(99 * 9), 512, 0, stream>>>(x_bf, wq_bf, q_bias, v_bias, q_buf, k_buf, v_buf);
  attn<<<dim3(NH, BATCH), 256, 0, stream>>>(q_buf, k_buf, v_buf, relb, ao_bf);
  gemm_proj<<<dim3(99 * 3), 512, 0, stream>>>(ao_bf, wp_bf, proj_b, out);
}

// Round 6
// 376.273 us; speedup vs baseline: 1.3518x; 1.3518x over previous
//
#include <hip/hip_runtime.h>

typedef unsigned short u16;
typedef __attribute__((ext_vector_type(8))) short short8;
typedef __attribute__((ext_vector_type(8))) __bf16 bf16x8;
typedef __attribute__((ext_vector_type(4))) float floatx4;

#define BATCH 128
#define SEQ 197
#define CH 768
#define NH 12
#define HD 64
#define MROWS (BATCH * SEQ)   // 25216 = 197 * 128 exactly
#define QKVC (3 * CH)         // 2304 unified qkv row width

__device__ __forceinline__ floatx4 mfma16(short8 a, short8 b, floatx4 c) {
  return __builtin_amdgcn_mfma_f32_16x16x32_bf16(
      __builtin_bit_cast(bf16x8, a), __builtin_bit_cast(bf16x8, b), c, 0, 0, 0);
}

__device__ __forceinline__ u16 f2bf(float f) {
  unsigned u = __builtin_bit_cast(unsigned, f);
  return (u16)((u + 0x7fffu + ((u >> 16) & 1u)) >> 16);
}

// async global->LDS, 16B per lane; LDS dest is wave-uniform base + lane*16
__device__ __forceinline__ void async16(const u16* g, u16* s) {
  __builtin_amdgcn_global_load_lds((const __attribute__((address_space(1))) void*)g,
                                   (__attribute__((address_space(3))) void*)s, 16, 0, 0);
}

// ---------------- fused preprocessing: 3x fp32->bf16 + relb gather ----------------
__global__ __launch_bounds__(256) void preproc(const float4* __restrict__ x, ushort4* __restrict__ xo, int n0,
                                               const float4* __restrict__ w1, ushort4* __restrict__ w1o, int n1,
                                               const float4* __restrict__ w2, ushort4* __restrict__ w2o, int n2,
                                               const int* __restrict__ idx, const float* __restrict__ table,
                                               float* __restrict__ relb) {
  int i = blockIdx.x * 256 + threadIdx.x;
  const float4* in; ushort4* out; int j;
  if (i < n0) { in = x; out = xo; j = i; }
  else if (i < n0 + n1) { in = w1; out = w1o; j = i - n0; }
  else if (i < n0 + n1 + n2) { in = w2; out = w2o; j = i - n0 - n1; }
  else {
    int t = i - (n0 + n1 + n2);
    if (t < SEQ * SEQ) {
      int id = idx[t];
      const float* row = table + id * NH;
#pragma unroll
      for (int h = 0; h < NH; h++) relb[h * (SEQ * SEQ) + t] = row[h];
    }
    return;
  }
  float4 v = in[j];
  ushort4 o;
  o.x = f2bf(v.x); o.y = f2bf(v.y); o.z = f2bf(v.z); o.w = f2bf(v.w);
  out[j] = o;
}

// ---------------- QKV GEMM: 128x256 tile, XOR-swizzled LDS, 3-stage pipeline vmcnt(6) ----------------
// grid 1773 (= 197 m-blocks x 9 n-blocks) 1-D, XCD-chunked swizzle. block 256 = 4 waves. BK=32.
// Output: unified row-major qkv[MROWS][2304] (full-line coalesced writes, no scatter).
__global__ __launch_bounds__(256, 2) void gemm_qkv(const u16* __restrict__ A,
                                                   const u16* __restrict__ W,
                                                   const float* __restrict__ qb,
                                                   const float* __restrict__ vb,
                                                   u16* __restrict__ qkv) {
  __shared__ u16 S[3][(128 + 256) * 32];   // 72 KB
  const int BUF = (128 + 256) * 32;
  const int BOFF = 128 * 32;
  const int NT = CH / 32;                  // 24 K-tiles
  int tid = threadIdx.x;
  int wave = tid >> 6, lane = tid & 63, quad = lane >> 4, c16 = lane & 15;
  int wm = wave >> 1, wn = wave & 1;

  int nwg = gridDim.x;                 // 1773
  int orig = blockIdx.x;
  int xcd = orig & 7, pos = orig >> 3;
  int qq = nwg >> 3, rr = nwg & 7;
  int lid = (xcd < rr ? xcd * (qq + 1) : rr * (qq + 1) + (xcd - rr) * qq) + pos;
  int mblk = lid / 9, nblk = lid - mblk * 9;
  int m0 = mblk * 128, n0 = nblk * 256;

  int lrow = lane >> 2;
  int lcol = (((lane & 3) ^ ((lane >> 3) & 3))) * 8;   // swizzled source col-group
  const u16* Ag0 = A + (size_t)(m0 + wave * 32 + lrow) * CH + lcol;
  const u16* Ag1 = Ag0 + (size_t)16 * CH;
  const u16* Bg0 = W + (size_t)(n0 + wave * 64 + lrow) * CH + lcol;
  const u16* Bg1 = Bg0 + (size_t)16 * CH;
  const u16* Bg2 = Bg0 + (size_t)32 * CH;
  const u16* Bg3 = Bg0 + (size_t)48 * CH;
  int aw0 = (wave * 32) * 32;
  int aw1 = (wave * 32 + 16) * 32;
  int bw0 = BOFF + (wave * 64) * 32;
  int bw1 = BOFF + (wave * 64 + 16) * 32;
  int bw2 = BOFF + (wave * 64 + 32) * 32;
  int bw3 = BOFF + (wave * 64 + 48) * 32;
  int fsl = (quad ^ ((c16 >> 1) & 3)) * 8;             // swizzled fragment slot
  int aro = (wm * 64 + c16) * 32 + fsl;
  int bro = BOFF + (wn * 128 + c16) * 32 + fsl;

  floatx4 acc[4][8] = {};
  u16* sbase = &S[0][0];

#define STAGE(kk_, sn_)                                                        \
  do {                                                                         \
    async16(Ag0 + (kk_), (sn_) + aw0);                                         \
    async16(Ag1 + (kk_), (sn_) + aw1);                                         \
    async16(Bg0 + (kk_), (sn_) + bw0);                                         \
    async16(Bg1 + (kk_), (sn_) + bw1);                                         \
    async16(Bg2 + (kk_), (sn_) + bw2);                                         \
    async16(Bg3 + (kk_), (sn_) + bw3);                                         \
  } while (0)

#define COMPUTE(sc_)                                                           \
  do {                                                                         \
    const u16* sc = (sc_);                                                     \
    short8 af[4], bfr[8];                                                      \
    _Pragma("unroll")                                                          \
    for (int i = 0; i < 4; i++) af[i] = *(const short8*)(sc + aro + i * 16 * 32); \
    _Pragma("unroll")                                                          \
    for (int j = 0; j < 8; j++) bfr[j] = *(const short8*)(sc + bro + j * 16 * 32); \
    _Pragma("unroll")                                                          \
    for (int i = 0; i < 4; i++)                                                \
      _Pragma("unroll")                                                        \
      for (int j = 0; j < 8; j++) acc[i][j] = mfma16(af[i], bfr[j], acc[i][j]); \
  } while (0)

  STAGE(0, sbase);
  STAGE(32, sbase + BUF);
  asm volatile("s_waitcnt vmcnt(6)" ::: "memory");
  __builtin_amdgcn_s_barrier();
  asm volatile("" ::: "memory");

  int cc = 0, ss = 2;
  for (int kt = 0; kt < NT - 2; ++kt) {
    STAGE((kt + 2) * 32, sbase + ss * BUF);
    COMPUTE(sbase + cc * BUF);
    asm volatile("s_waitcnt vmcnt(6)" ::: "memory");
    __builtin_amdgcn_s_barrier();
    asm volatile("" ::: "memory");
    cc = cc == 2 ? 0 : cc + 1;
    ss = ss == 2 ? 0 : ss + 1;
  }
  COMPUTE(sbase + cc * BUF);
  asm volatile("s_waitcnt vmcnt(0)" ::: "memory");
  __builtin_amdgcn_s_barrier();
  asm volatile("" ::: "memory");
  cc = cc == 2 ? 0 : cc + 1;
  COMPUTE(sbase + cc * BUF);

#undef STAGE
#undef COMPUTE

#pragma unroll
  for (int j = 0; j < 8; j++) {
    int gcol = n0 + wn * 128 + j * 16 + c16;   // 0..2303
    float badd = (gcol < CH) ? qb[gcol] : (gcol >= 2 * CH ? vb[gcol - 2 * CH] : 0.0f);
#pragma unroll
    for (int i = 0; i < 4; i++) {
#pragma unroll
      for (int r = 0; r < 4; r++) {
        int grow = m0 + wm * 64 + i * 16 + quad * 4 + r;
        qkv[(size_t)grow * QKVC + gcol] = f2bf(acc[i][j][r] + badd);
      }
    }
  }
}

// ---------------- attention: one block per (h, b), register softmax, deferred 1/sum ----------------
#define PS 232
#define VS 264

__global__ __launch_bounds__(256, 2) void attn(const u16* __restrict__ qkv,
                                               const float* __restrict__ relb,
                                               u16* __restrict__ attn_out) {
  __shared__ u16 Vt[64 * VS];
  __shared__ u16 P[4 * 16 * PS];

  int h = blockIdx.x, b = blockIdx.y;
  int tid = threadIdx.x, wave = tid >> 6, lane = tid & 63, quad = lane >> 4, c16 = lane & 15;
  const u16* Q = qkv + (size_t)b * SEQ * QKVC + h * HD;            // row stride QKVC
  const u16* Kp = Q + CH;
  const u16* Vp = Q + 2 * CH;
  const float* RB = relb + (size_t)h * (SEQ * SEQ);

  {
    int mrow = tid >> 3, dbase = (tid & 7) * 8;
#pragma unroll
    for (int i = 0; i < 7; i++) {
      int m = mrow + 32 * i;
      if (m < SEQ) {
        ushort4 v0 = *(const ushort4*)(Vp + (size_t)m * QKVC + dbase);
        ushort4 v1 = *(const ushort4*)(Vp + (size_t)m * QKVC + dbase + 4);
        Vt[(dbase + 0) * VS + m] = v0.x;
        Vt[(dbase + 1) * VS + m] = v0.y;
        Vt[(dbase + 2) * VS + m] = v0.z;
        Vt[(dbase + 3) * VS + m] = v0.w;
        Vt[(dbase + 4) * VS + m] = v1.x;
        Vt[(dbase + 5) * VS + m] = v1.y;
        Vt[(dbase + 6) * VS + m] = v1.z;
        Vt[(dbase + 7) * VS + m] = v1.w;
      } else {
#pragma unroll
        for (int dd = 0; dd < 8; dd++) Vt[(dbase + dd) * VS + m] = 0;
      }
    }
  }
  __syncthreads();

  u16* Pw = P + wave * 16 * PS;
  for (int rt = wave; rt < 13; rt += 4) {
    int q0 = rt * 16;
    int qr = min(q0 + c16, SEQ - 1);
    short8 qa0 = *(const short8*)(Q + (size_t)qr * QKVC + quad * 8);
    short8 qa1 = *(const short8*)(Q + (size_t)qr * QKVC + 32 + quad * 8);

    floatx4 sacc[13];
    __builtin_amdgcn_s_setprio(1);
#pragma unroll
    for (int nt = 0; nt < 13; nt++) {
      int mc = min(nt * 16 + c16, SEQ - 1);
      floatx4 a = {0.f, 0.f, 0.f, 0.f};
      a = mfma16(qa0, *(const short8*)(Kp + (size_t)mc * QKVC + quad * 8), a);
      a = mfma16(qa1, *(const short8*)(Kp + (size_t)mc * QKVC + 32 + quad * 8), a);
      sacc[nt] = a;
    }
    __builtin_amdgcn_s_setprio(0);

    float invr[4];
#pragma unroll
    for (int r = 0; r < 4; r++) {
      int rq = min(q0 + quad * 4 + r, SEQ - 1);
      const float* RBr = RB + (size_t)rq * SEQ;
      float mx = -1e30f;
#pragma unroll
      for (int nt = 0; nt < 13; nt++) {
        int m = nt * 16 + c16;
        float s = -1e30f;
        if (m < SEQ) s = sacc[nt][r] * 0.125f + RBr[m];
        sacc[nt][r] = s;
        mx = fmaxf(mx, s);
      }
      mx = fmaxf(mx, __shfl_xor(mx, 1));
      mx = fmaxf(mx, __shfl_xor(mx, 2));
      mx = fmaxf(mx, __shfl_xor(mx, 4));
      mx = fmaxf(mx, __shfl_xor(mx, 8));
      float sum = 0.f;
#pragma unroll
      for (int nt = 0; nt < 13; nt++) {
        float e = __expf(sacc[nt][r] - mx);
        sacc[nt][r] = e;
        sum += e;
      }
      sum += __shfl_xor(sum, 1);
      sum += __shfl_xor(sum, 2);
      sum += __shfl_xor(sum, 4);
      sum += __shfl_xor(sum, 8);
      invr[r] = 1.f / sum;
      int prow = (quad * 4 + r) * PS;
#pragma unroll
      for (int nt = 0; nt < 13; nt++)
        Pw[prow + nt * 16 + c16] = f2bf(sacc[nt][r]);   // unnormalized (e <= 1)
      Pw[prow + 208 + c16] = 0;
    }

    floatx4 oacc[4] = {};
    __builtin_amdgcn_s_setprio(1);
#pragma unroll
    for (int ks = 0; ks < 7; ks++) {
      short8 a = *(const short8*)(Pw + c16 * PS + ks * 32 + quad * 8);
#pragma unroll
      for (int dt = 0; dt < 4; dt++) {
        short8 bb = *(const short8*)(Vt + (dt * 16 + c16) * VS + ks * 32 + quad * 8);
        oacc[dt] = mfma16(a, bb, oacc[dt]);
      }
    }
    __builtin_amdgcn_s_setprio(0);
#pragma unroll
    for (int dt = 0; dt < 4; dt++) {
      int d = dt * 16 + c16;
#pragma unroll
      for (int r = 0; r < 4; r++) {
        int grow = q0 + quad * 4 + r;
        if (grow < SEQ)
          attn_out[((size_t)b * SEQ + grow) * CH + h * HD + d] = f2bf(oacc[dt][r] * invr[r]);
      }
    }
  }
}

// ---------------- proj GEMM: 128x256 tile, XOR-swizzled LDS, 3-stage pipeline, fp32 out ----------------
// grid 591 (= 197 m-blocks x 3 n-blocks) 1-D, XCD-chunked swizzle.
__global__ __launch_bounds__(256, 2) void gemm_proj(const u16* __restrict__ A,
                                                    const u16* __restrict__ W,
                                                    const float* __restrict__ bias,
                                                    float* __restrict__ out) {
  __shared__ u16 S[3][(128 + 256) * 32];
  const int BUF = (128 + 256) * 32;
  const int BOFF = 128 * 32;
  const int NT = CH / 32;
  int tid = threadIdx.x;
  int wave = tid >> 6, lane = tid & 63, quad = lane >> 4, c16 = lane & 15;
  int wm = wave >> 1, wn = wave & 1;

  int nwg = gridDim.x;                 // 591
  int orig = blockIdx.x;
  int xcd = orig & 7, pos = orig >> 3;
  int qq = nwg >> 3, rr = nwg & 7;
  int lid = (xcd < rr ? xcd * (qq + 1) : rr * (qq + 1) + (xcd - rr) * qq) + pos;
  int mblk = lid / 3, nblk = lid - mblk * 3;
  int m0 = mblk * 128, n0 = nblk * 256;

  int lrow = lane >> 2;
  int lcol = (((lane & 3) ^ ((lane >> 3) & 3))) * 8;
  const u16* Ag0 = A + (size_t)(m0 + wave * 32 + lrow) * CH + lcol;
  const u16* Ag1 = Ag0 + (size_t)16 * CH;
  const u16* Bg0 = W + (size_t)(n0 + wave * 64 + lrow) * CH + lcol;
  const u16* Bg1 = Bg0 + (size_t)16 * CH;
  const u16* Bg2 = Bg0 + (size_t)32 * CH;
  const u16* Bg3 = Bg0 + (size_t)48 * CH;
  int aw0 = (wave * 32) * 32;
  int aw1 = (wave * 32 + 16) * 32;
  int bw0 = BOFF + (wave * 64) * 32;
  int bw1 = BOFF + (wave * 64 + 16) * 32;
  int bw2 = BOFF + (wave * 64 + 32) * 32;
  int bw3 = BOFF + (wave * 64 + 48) * 32;
  int fsl = (quad ^ ((c16 >> 1) & 3)) * 8;
  int aro = (wm * 64 + c16) * 32 + fsl;
  int bro = BOFF + (wn * 128 + c16) * 32 + fsl;

  floatx4 acc[4][8] = {};
  u16* sbase = &S[0][0];

#define STAGE(kk_, sn_)                                                        \
  do {                                                                         \
    async16(Ag0 + (kk_), (sn_) + aw0);                                         \
    async16(Ag1 + (kk_), (sn_) + aw1);                                         \
    async16(Bg0 + (kk_), (sn_) + bw0);                                         \
    async16(Bg1 + (kk_), (sn_) + bw1);                                         \
    async16(Bg2 + (kk_), (sn_) + bw2);                                         \
    async16(Bg3 + (kk_), (sn_) + bw3);                                         \
  } while (0)

#define COMPUTE(sc_)                                                           \
  do {                                                                         \
    const u16* sc = (sc_);                                                     \
    short8 af[4], bfr[8];                                                      \
    _Pragma("unroll")                                                          \
    for (int i = 0; i < 4; i++) af[i] = *(const short8*)(sc + aro + i * 16 * 32); \
    _Pragma("unroll")                                                          \
    for (int j = 0; j < 8; j++) bfr[j] = *(const short8*)(sc + bro + j * 16 * 32); \
    _Pragma("unroll")                                                          \
    for (int i = 0; i < 4; i++)                                                \
      _Pragma("unroll")                                                        \
      for (int j = 0; j < 8; j++) acc[i][j] = mfma16(af[i], bfr[j], acc[i][j]); \
  } while (0)

  STAGE(0, sbase);
  STAGE(32, sbase + BUF);
  asm volatile("s_waitcnt vmcnt(6)" ::: "memory");
  __builtin_amdgcn_s_barrier();
  asm volatile("" ::: "memory");

  int cc = 0, ss = 2;
  for (int kt = 0; kt < NT - 2; ++kt) {
    STAGE((kt + 2) * 32, sbase + ss * BUF);
    COMPUTE(sbase + cc * BUF);
    asm volatile("s_waitcnt vmcnt(6)" ::: "memory");
    __builtin_amdgcn_s_barrier();
    asm volatile("" ::: "memory");
    cc = cc == 2 ? 0 : cc + 1;
    ss = ss == 2 ? 0 : ss + 1;
  }
  COMPUTE(sbase + cc * BUF);
  asm volatile("s_waitcnt vmcnt(0)" ::: "memory");
  __builtin_amdgcn_s_barrier();
  asm volatile("" ::: "memory");
  cc = cc == 2 ? 0 : cc + 1;
  COMPUTE(sbase + cc * BUF);

#undef STAGE
#undef COMPUTE

#pragma unroll
  for (int j = 0; j < 8; j++) {
    int gcol = n0 + wn * 128 + j * 16 + c16;
    float bj = bias[gcol];
#pragma unroll
    for (int i = 0; i < 4; i++)
#pragma unroll
      for (int r = 0; r < 4; r++) {
        int grow = m0 + wm * 64 + i * 16 + quad * 4 + r;
        out[(size_t)grow * CH + gcol] = acc[i][j][r] + bj;
      }
  }
}

extern "C" void kernel_launch(void* const* d_in, const int* in_sizes, int n_in,
                              void* d_out, int out_size, void* d_ws, size_t ws_size,
                              hipStream_t stream) {
  const float* x      = (const float*)d_in[0];
  const float* qkv_w  = (const float*)d_in[1];
  const float* q_bias = (const float*)d_in[2];
  const float* v_bias = (const float*)d_in[3];
  const float* table  = (const float*)d_in[4];
  const float* proj_w = (const float*)d_in[5];
  const float* proj_b = (const float*)d_in[6];
  const int*   rel_ix = (const int*)d_in[7];
  float* out = (float*)d_out;

  char* ws = (char*)d_ws;
  size_t off = 0;
  u16* x_bf    = (u16*)(ws + off); off += (size_t)MROWS * CH * 2;
  u16* wq_bf   = (u16*)(ws + off); off += (size_t)3 * CH * CH * 2;
  u16* wp_bf   = (u16*)(ws + off); off += (size_t)CH * CH * 2;
  u16* qkv_buf = (u16*)(ws + off); off += (size_t)MROWS * QKVC * 2;
  u16* ao_bf   = (u16*)(ws + off); off += (size_t)MROWS * CH * 2;
  float* relb  = (float*)(ws + off);

  int n0 = MROWS * CH / 4;
  int n1 = 3 * CH * CH / 4;
  int n2 = CH * CH / 4;
  int ntot = n0 + n1 + n2 + SEQ * SEQ;
  preproc<<<(ntot + 255) / 256, 256, 0, stream>>>(
      (const float4*)x, (ushort4*)x_bf, n0,
      (const float4*)qkv_w, (ushort4*)wq_bf, n1,
      (const float4*)proj_w, (ushort4*)wp_bf, n2,
      rel_ix, table, relb);
  gemm_qkv<<<dim3(197 * 9), 256, 0, stream>>>(x_bf, wq_bf, q_bias, v_bias, qkv_buf);
  attn<<<dim3(NH, BATCH), 256, 0, stream>>>(qkv_buf, relb, ao_bf);
  gemm_proj<<<dim3(197 * 3), 256, 0, stream>>>(ao_bf, wp_bf, proj_b, out);
}